// Round 3
// baseline (265.075 us; speedup 1.0000x reference)
//
#include <hip/hip_runtime.h>

// out[b,k,l,f] = x[b, src(k,l), f], B=32, L=128, F=64, K=2L=256, fp32.
//   k <  L: src = (l - k) mod L   (cyclic)
//   k >= L: src = (k - l) mod L   (reflected)
//
// Round-5: round-3 slice-linear multicast + NONTEMPORAL stores (compile fix:
// __builtin_nontemporal_store requires a native clang vector type, not
// HIP_vector_type<float,4> — use ext_vector_type(4) and reinterpret).
//
// Evidence trail: dur_us = ~163us re-poison fill (rocprof top-5 all
// fillBuffer; our kernel absent -> kernel < 162us) + ~90us kernel.
// Round-2 (scattered 1 KiB fragments, 32 w/CU) and round-3 (pure linear
// slices, 16 w/CU) BOTH run ~90us => address pattern & occupancy are NOT
// the limiter. fillBuffer hits 6.6 TB/s at ~3 waves/CU. The remaining
// structural difference: ordinary stores WRITE-ALLOCATE in L2; streaming
// 256 MiB of dirty lines through 32 MiB aggregate L2 halves the rate
// (allocate + writeback per line). Fix: global_store_dwordx4 nt —
// bypass L2 allocation, stream to HBM.
//
// Structure (unchanged from round-3): block (b,kbsel) holds 8 source rows
// in registers; writes 8 whole 32 KiB (b,k) slices end-to-end linearly
// (thread t -> slice_base + t + 256*j2). Register index (+/-(j2-m))&7 is
// compile-time after full unroll. Loads of x stay CACHED (reused by 32
// blocks per batch).
//
// Grid: 32 b x 32 kbsel = 1024 blocks x 256 thr. Per thread: 8 cached
// loads (L2-hit), 64 independent nt stores.

typedef float f32x4 __attribute__((ext_vector_type(4)));

__global__ __launch_bounds__(256) void SymmetryExpansion_kernel(
    const f32x4* __restrict__ x, f32x4* __restrict__ out) {
    unsigned t  = threadIdx.x;
    unsigned f4 = t & 15u;        // float4 chunk within F=64
    unsigned w  = t >> 4;         // l-group / row-group within block, 0..15

    unsigned blk   = blockIdx.x;
    unsigned kbsel = blk & 31u;   // 0..15 cyclic, 16..31 reflected
    unsigned b     = blk >> 5;    // batch

    bool refl   = (kbsel >= 16u);
    unsigned kb = refl ? (kbsel + 112u) : kbsel;  // 128..143 | 0..15

    // Held source rows:
    //   cyclic   : row_j = (w - kb + 16*j) mod 128
    //   reflected: row_j = (kb - w + 16*j) mod 128
    unsigned rbase = refl ? (kb - w) : (w + 128u - kb);

    // x is (32,128,64) fp32 -> float4 index (b<<11)|(row<<4)|f4
    const f32x4* xb = x + (b << 11) + f4;
    f32x4 r[8];
#pragma unroll
    for (unsigned j = 0; j < 8u; ++j)
        r[j] = xb[((rbase + (j << 4)) & 127u) << 4];

    // out float4 index: (b<<19)|(k<<11)|(l<<4)|f4. Slice m is k = kb+16m
    // (stride 16 slices = 1<<15 float4). Thread t's store offsets within a
    // slice are t + 256*j2 -> the workgroup covers the 32 KiB slice linearly.
    f32x4* ob = out + (b << 19) + (kb << 11) + t;
    if (!refl) {
        // value at l = w + 16*j2 is x[b,(l-k)&127] = r[(j2-m)&7]
#pragma unroll
        for (unsigned m = 0; m < 8u; ++m)
#pragma unroll
            for (unsigned j2 = 0; j2 < 8u; ++j2)
                __builtin_nontemporal_store(r[(j2 - m) & 7u],
                                            &ob[(m << 15) + (j2 << 8)]);
    } else {
        // value at l = w + 16*j2 is x[b,(k-l)&127] = r[(m-j2)&7]
#pragma unroll
        for (unsigned m = 0; m < 8u; ++m)
#pragma unroll
            for (unsigned j2 = 0; j2 < 8u; ++j2)
                __builtin_nontemporal_store(r[(m - j2) & 7u],
                                            &ob[(m << 15) + (j2 << 8)]);
    }
}

extern "C" void kernel_launch(void* const* d_in, const int* in_sizes, int n_in,
                              void* d_out, int out_size, void* d_ws, size_t ws_size,
                              hipStream_t stream) {
    const f32x4* x = (const f32x4*)d_in[0];
    f32x4* out = (f32x4*)d_out;
    dim3 grid(1024), block(256);
    hipLaunchKernelGGL(SymmetryExpansion_kernel, grid, block, 0, stream, x, out);
}